// Round 1
// baseline (542.259 us; speedup 1.0000x reference)
//
#include <hip/hip_runtime.h>

#define B_ 2
#define C_ 64
#define H_ 192
#define W_ 384
#define K_ 8
constexpr int HW_ = H_ * W_;
constexpr int CHW_ = C_ * HW_;
constexpr int NP_ = B_ * HW_;   // 147456, divisible by 256

__global__ __launch_bounds__(256) void relprop_kernel(
    const float* __restrict__ feat, const int* __restrict__ mask,
    const float* __restrict__ Wo, const float* __restrict__ bo,
    const float* __restrict__ Ww, const float* __restrict__ bw,
    float* __restrict__ out) {
  const int p = blockIdx.x * blockDim.x + threadIdx.x;
  const int b = p / HW_;
  const int hw = p - b * HW_;
  const int y = hw / W_;
  const int x = hw - y * W_;
  const float* fb = feat + b * CHW_;

  // ---- Stage 1: 24 channel dot-products (16 offsets + 8 logits) ----
  float acc[24];
#pragma unroll
  for (int i = 0; i < 16; ++i) acc[i] = bo[i];
#pragma unroll
  for (int i = 0; i < 8; ++i) acc[16 + i] = bw[i];

#pragma unroll
  for (int c = 0; c < C_; ++c) {
    const float v = fb[c * HW_ + hw];   // coalesced across threads
#pragma unroll
    for (int i = 0; i < 16; ++i) acc[i] = fmaf(Wo[i * C_ + c], v, acc[i]);
#pragma unroll
    for (int i = 0; i < 8; ++i) acc[16 + i] = fmaf(Ww[i * C_ + c], v, acc[16 + i]);
  }

  // ---- Stage 2: softmax over K, fold mask and 1/sum into weights ----
  float m = acc[16];
#pragma unroll
  for (int k = 1; k < K_; ++k) m = fmaxf(m, acc[16 + k]);
  float wt[K_];
  float s = 0.f;
#pragma unroll
  for (int k = 0; k < K_; ++k) { wt[k] = __expf(acc[16 + k] - m); s += wt[k]; }
  const float fm = (mask[p] != 0) ? 1.f : 0.f;
  const float inv = fm / s;
#pragma unroll
  for (int k = 0; k < K_; ++k) wt[k] *= inv;

  // ---- Stage 3: bilinear gather-accumulate ----
  float res[C_];
#pragma unroll
  for (int c = 0; c < C_; ++c) res[c] = 0.f;

  if (fm != 0.f) {   // exec-masked skip: masked lanes issue no gathers
#pragma unroll
    for (int k = 0; k < K_; ++k) {
      const float px = (float)x + acc[2 * k];
      const float py = (float)y + acc[2 * k + 1];
      const float x0f = floorf(px), y0f = floorf(py);
      const float wx = px - x0f, wy = py - y0f;
      const int x0 = (int)x0f, y0 = (int)y0f;
      const int x1 = x0 + 1, y1 = y0 + 1;
      const bool vx0 = ((unsigned)x0 < (unsigned)W_);
      const bool vx1 = ((unsigned)x1 < (unsigned)W_);
      const bool vy0 = ((unsigned)y0 < (unsigned)H_);
      const bool vy1 = ((unsigned)y1 < (unsigned)H_);
      const int cx0 = min(max(x0, 0), W_ - 1), cx1 = min(max(x1, 0), W_ - 1);
      const int cy0 = min(max(y0, 0), H_ - 1), cy1 = min(max(y1, 0), H_ - 1);
      const float wk = wt[k];
      const float w00 = wk * (1.f - wx) * (1.f - wy) * ((vx0 && vy0) ? 1.f : 0.f);
      const float w01 = wk * wx * (1.f - wy) * ((vx1 && vy0) ? 1.f : 0.f);
      const float w10 = wk * (1.f - wx) * wy * ((vx0 && vy1) ? 1.f : 0.f);
      const float w11 = wk * wx * wy * ((vx1 && vy1) ? 1.f : 0.f);
      const int i00 = cy0 * W_ + cx0, i01 = cy0 * W_ + cx1;
      const int i10 = cy1 * W_ + cx0, i11 = cy1 * W_ + cx1;
#pragma unroll
      for (int c = 0; c < C_; ++c) {
        const float* fc = fb + c * HW_;
        res[c] += w00 * fc[i00] + w01 * fc[i01] + w10 * fc[i10] + w11 * fc[i11];
      }
    }
  }

  // ---- Epilogue: out = feat + residual (mask already folded) ----
#pragma unroll
  for (int c = 0; c < C_; ++c)
    out[b * CHW_ + c * HW_ + hw] = fb[c * HW_ + hw] + res[c];
}

extern "C" void kernel_launch(void* const* d_in, const int* in_sizes, int n_in,
                              void* d_out, int out_size, void* d_ws, size_t ws_size,
                              hipStream_t stream) {
  const float* feat = (const float*)d_in[0];
  const int* mask = (const int*)d_in[1];
  const float* Wo = (const float*)d_in[2];
  const float* bo = (const float*)d_in[3];
  const float* Ww = (const float*)d_in[4];
  const float* bw = (const float*)d_in[5];
  float* out = (float*)d_out;

  dim3 grid(NP_ / 256), block(256);
  hipLaunchKernelGGL(relprop_kernel, grid, block, 0, stream,
                     feat, mask, Wo, bo, Ww, bw, out);
}

// Round 2
// 296.469 us; speedup vs baseline: 1.8291x; 1.8291x over previous
//
#include <hip/hip_runtime.h>

#define B_ 2
#define C_ 64
#define H_ 192
#define W_ 384
#define K_ 8
constexpr int HW_ = H_ * W_;
constexpr int CHW_ = C_ * HW_;
constexpr int NP_ = B_ * HW_;           // 147456
constexpr int NB_ = NP_ / 64;           // 2304 gather blocks (64 px each), %8==0
constexpr size_t WS_NEED_ = (size_t)24 * NP_ * sizeof(float);  // px/py/wt planes

// ---------------- Kernel A: 1x1 convs + softmax + mask fold ----------------
__global__ __launch_bounds__(256) void prep_kernel(
    const float* __restrict__ feat, const int* __restrict__ mask,
    const float* __restrict__ Wo, const float* __restrict__ bo,
    const float* __restrict__ Ww, const float* __restrict__ bw,
    float* __restrict__ ws) {
  const int p = blockIdx.x * 256 + threadIdx.x;
  const int b = p / HW_;
  const int hw = p - b * HW_;
  const int y = hw / W_;
  const int x = hw - y * W_;
  const float* fb = feat + b * CHW_;

  float acc[24];
#pragma unroll
  for (int i = 0; i < 16; ++i) acc[i] = bo[i];
#pragma unroll
  for (int i = 0; i < 8; ++i) acc[16 + i] = bw[i];
#pragma unroll
  for (int c = 0; c < C_; ++c) {
    const float v = fb[c * HW_ + hw];   // coalesced
#pragma unroll
    for (int i = 0; i < 16; ++i) acc[i] = fmaf(Wo[i * C_ + c], v, acc[i]);
#pragma unroll
    for (int i = 0; i < 8; ++i) acc[16 + i] = fmaf(Ww[i * C_ + c], v, acc[16 + i]);
  }

  float m = acc[16];
#pragma unroll
  for (int k = 1; k < K_; ++k) m = fmaxf(m, acc[16 + k]);
  float wt[K_];
  float s = 0.f;
#pragma unroll
  for (int k = 0; k < K_; ++k) { wt[k] = __expf(acc[16 + k] - m); s += wt[k]; }
  const float fm = (mask[p] != 0) ? 1.f : 0.f;
  const float inv = fm / s;

#pragma unroll
  for (int k = 0; k < K_; ++k) {
    ws[k * NP_ + p]        = (float)x + acc[2 * k];       // px
    ws[(8 + k) * NP_ + p]  = (float)y + acc[2 * k + 1];   // py
    ws[(16 + k) * NP_ + p] = wt[k] * inv;                 // folded weight
  }
}

// ---------------- Kernel B: gather + residual add ----------------
// Block = 256 threads = 4 waves. Each wave: 64 consecutive pixels x 16 channels.
__global__ __launch_bounds__(256) void gather_kernel(
    const float* __restrict__ feat, const float* __restrict__ ws,
    float* __restrict__ out) {
  // bijective XCD-chunked swizzle: XCD i gets contiguous band of NB_/8 strips
  const int bid = blockIdx.x;
  const int sb = (bid & 7) * (NB_ / 8) + (bid >> 3);
  const int lane = threadIdx.x & 63;
  const int wv = threadIdx.x >> 6;            // 0..3, uniform per wave
  const int p = sb * 64 + lane;               // 64 consecutive pixels per wave
  const int b = p / HW_;
  const int hw = p - b * HW_;
  const float* fb = feat + b * CHW_;
  const int cbase = wv * 16;

  float wt[K_];
#pragma unroll
  for (int k = 0; k < K_; ++k) wt[k] = ws[(16 + k) * NP_ + p];
  float res[16];
#pragma unroll
  for (int c = 0; c < 16; ++c) res[c] = 0.f;

  float s8 = 0.f;
#pragma unroll
  for (int k = 0; k < K_; ++k) s8 += wt[k];

  if (s8 != 0.f) {                            // masked-off lanes skip gathers
#pragma unroll
    for (int k = 0; k < K_; ++k) {
      const float px = ws[k * NP_ + p];
      const float py = ws[(8 + k) * NP_ + p];
      const float x0f = floorf(px), y0f = floorf(py);
      const float wx = px - x0f, wy = py - y0f;
      const int x0 = (int)x0f, y0 = (int)y0f;
      const int x1 = x0 + 1, y1 = y0 + 1;
      const bool vx0 = ((unsigned)x0 < (unsigned)W_);
      const bool vx1 = ((unsigned)x1 < (unsigned)W_);
      const bool vy0 = ((unsigned)y0 < (unsigned)H_);
      const bool vy1 = ((unsigned)y1 < (unsigned)H_);
      const int cx0 = min(max(x0, 0), W_ - 1), cx1 = min(max(x1, 0), W_ - 1);
      const int cy0 = min(max(y0, 0), H_ - 1), cy1 = min(max(y1, 0), H_ - 1);
      const float wk = wt[k];
      const float w00 = wk * (1.f - wx) * (1.f - wy) * ((vx0 && vy0) ? 1.f : 0.f);
      const float w01 = wk * wx * (1.f - wy) * ((vx1 && vy0) ? 1.f : 0.f);
      const float w10 = wk * (1.f - wx) * wy * ((vx0 && vy1) ? 1.f : 0.f);
      const float w11 = wk * wx * wy * ((vx1 && vy1) ? 1.f : 0.f);
      const int i00 = cy0 * W_ + cx0, i01 = cy0 * W_ + cx1;
      const int i10 = cy1 * W_ + cx0, i11 = cy1 * W_ + cx1;
      const float* fc = fb + cbase * HW_;
#pragma unroll
      for (int c = 0; c < 16; ++c) {
        res[c] = fmaf(w00, fc[i00], res[c]);
        res[c] = fmaf(w01, fc[i01], res[c]);
        res[c] = fmaf(w10, fc[i10], res[c]);
        res[c] = fmaf(w11, fc[i11], res[c]);
        fc += HW_;
      }
    }
  }

#pragma unroll
  for (int c = 0; c < 16; ++c) {
    const int off = b * CHW_ + (cbase + c) * HW_ + hw;
    out[off] = feat[off] + res[c];
  }
}

// ---------------- Fallback: round-1 fused kernel (if ws too small) ----------------
__global__ __launch_bounds__(256) void fused_kernel(
    const float* __restrict__ feat, const int* __restrict__ mask,
    const float* __restrict__ Wo, const float* __restrict__ bo,
    const float* __restrict__ Ww, const float* __restrict__ bw,
    float* __restrict__ out) {
  const int p = blockIdx.x * blockDim.x + threadIdx.x;
  const int b = p / HW_;
  const int hw = p - b * HW_;
  const int y = hw / W_;
  const int x = hw - y * W_;
  const float* fb = feat + b * CHW_;
  float acc[24];
#pragma unroll
  for (int i = 0; i < 16; ++i) acc[i] = bo[i];
#pragma unroll
  for (int i = 0; i < 8; ++i) acc[16 + i] = bw[i];
#pragma unroll
  for (int c = 0; c < C_; ++c) {
    const float v = fb[c * HW_ + hw];
#pragma unroll
    for (int i = 0; i < 16; ++i) acc[i] = fmaf(Wo[i * C_ + c], v, acc[i]);
#pragma unroll
    for (int i = 0; i < 8; ++i) acc[16 + i] = fmaf(Ww[i * C_ + c], v, acc[16 + i]);
  }
  float m = acc[16];
#pragma unroll
  for (int k = 1; k < K_; ++k) m = fmaxf(m, acc[16 + k]);
  float wt[K_];
  float s = 0.f;
#pragma unroll
  for (int k = 0; k < K_; ++k) { wt[k] = __expf(acc[16 + k] - m); s += wt[k]; }
  const float fm = (mask[p] != 0) ? 1.f : 0.f;
  const float inv = fm / s;
#pragma unroll
  for (int k = 0; k < K_; ++k) wt[k] *= inv;
  float res[C_];
#pragma unroll
  for (int c = 0; c < C_; ++c) res[c] = 0.f;
  if (fm != 0.f) {
#pragma unroll
    for (int k = 0; k < K_; ++k) {
      const float px = (float)x + acc[2 * k];
      const float py = (float)y + acc[2 * k + 1];
      const float x0f = floorf(px), y0f = floorf(py);
      const float wx = px - x0f, wy = py - y0f;
      const int x0 = (int)x0f, y0 = (int)y0f;
      const int x1 = x0 + 1, y1 = y0 + 1;
      const bool vx0 = ((unsigned)x0 < (unsigned)W_);
      const bool vx1 = ((unsigned)x1 < (unsigned)W_);
      const bool vy0 = ((unsigned)y0 < (unsigned)H_);
      const bool vy1 = ((unsigned)y1 < (unsigned)H_);
      const int cx0 = min(max(x0, 0), W_ - 1), cx1 = min(max(x1, 0), W_ - 1);
      const int cy0 = min(max(y0, 0), H_ - 1), cy1 = min(max(y1, 0), H_ - 1);
      const float wk = wt[k];
      const float w00 = wk * (1.f - wx) * (1.f - wy) * ((vx0 && vy0) ? 1.f : 0.f);
      const float w01 = wk * wx * (1.f - wy) * ((vx1 && vy0) ? 1.f : 0.f);
      const float w10 = wk * (1.f - wx) * wy * ((vx0 && vy1) ? 1.f : 0.f);
      const float w11 = wk * wx * wy * ((vx1 && vy1) ? 1.f : 0.f);
      const int i00 = cy0 * W_ + cx0, i01 = cy0 * W_ + cx1;
      const int i10 = cy1 * W_ + cx0, i11 = cy1 * W_ + cx1;
#pragma unroll
      for (int c = 0; c < C_; ++c) {
        const float* fc = fb + c * HW_;
        res[c] += w00 * fc[i00] + w01 * fc[i01] + w10 * fc[i10] + w11 * fc[i11];
      }
    }
  }
#pragma unroll
  for (int c = 0; c < C_; ++c)
    out[b * CHW_ + c * HW_ + hw] = fb[c * HW_ + hw] + res[c];
}

extern "C" void kernel_launch(void* const* d_in, const int* in_sizes, int n_in,
                              void* d_out, int out_size, void* d_ws, size_t ws_size,
                              hipStream_t stream) {
  const float* feat = (const float*)d_in[0];
  const int* mask = (const int*)d_in[1];
  const float* Wo = (const float*)d_in[2];
  const float* bo = (const float*)d_in[3];
  const float* Ww = (const float*)d_in[4];
  const float* bw = (const float*)d_in[5];
  float* out = (float*)d_out;

  if (ws_size >= WS_NEED_) {
    float* ws = (float*)d_ws;
    hipLaunchKernelGGL(prep_kernel, dim3(NP_ / 256), dim3(256), 0, stream,
                       feat, mask, Wo, bo, Ww, bw, ws);
    hipLaunchKernelGGL(gather_kernel, dim3(NB_), dim3(256), 0, stream,
                       feat, ws, out);
  } else {
    hipLaunchKernelGGL(fused_kernel, dim3(NP_ / 256), dim3(256), 0, stream,
                       feat, mask, Wo, bo, Ww, bw, out);
  }
}

// Round 3
// 103.157 us; speedup vs baseline: 5.2566x; 2.8739x over previous
//
#include <hip/hip_runtime.h>

#define B_ 2
#define C_ 64
#define H_ 192
#define W_ 384
#define K_ 8
constexpr int HW_ = H_ * W_;
constexpr int CHW_ = C_ * HW_;
constexpr int NP_ = B_ * HW_;           // 147456
constexpr int NBLK_ = NP_ / 64;         // 2304, %8==0

// ---- new ws partition (float units) ----
constexpr size_t FT_F   = (size_t)NP_ * 64;          // NHWC feat_t
constexpr size_t W4_F   = FT_F;                      // start of float4 weight planes (8*NP_ float4)
constexpr size_t XY_F   = W4_F + (size_t)8 * NP_ * 4;// start of int2 coord planes (8*NP_ int2)
constexpr size_t MK_F   = XY_F + (size_t)8 * NP_ * 2;// mask plane (NP_ floats)
constexpr size_t WS_NEED_NEW = (MK_F + NP_) * 4;     // ~66.6 MB
constexpr size_t WS_NEED_OLD = (size_t)24 * NP_ * sizeof(float);

// =================== Kernel P2: conv + softmax + records + NHWC transpose ===================
// grid 2304 x 256 thr; block covers 64 px; wave w loads channels [16w,16w+16)
__global__ __launch_bounds__(256) void prep2_kernel(
    const float* __restrict__ feat, const int* __restrict__ mask,
    const float* __restrict__ Wo, const float* __restrict__ bo,
    const float* __restrict__ Ww, const float* __restrict__ bw,
    float* __restrict__ ws) {
  __shared__ float lds[6144];   // phase1: [64 px][65] staging; phase3: [24][4][64] partials
  const int tid = threadIdx.x;
  const int lane = tid & 63;
  const int wv = tid >> 6;
  const int p0 = blockIdx.x * 64;
  const int b = p0 / HW_;
  const int hw0 = p0 - b * HW_;
  const int p_lane = p0 + lane;
  const int hw_lane = hw0 + lane;
  const float* fb = feat + (size_t)b * CHW_;

  // phase 1: coalesced channel loads, partial dot-products, LDS staging
  float pacc[24];
#pragma unroll
  for (int j = 0; j < 24; ++j) pacc[j] = 0.f;
#pragma unroll
  for (int cc = 0; cc < 16; ++cc) {
    const int c = wv * 16 + cc;                    // wave-uniform -> s_load weights
    const float v = fb[(size_t)c * HW_ + hw_lane]; // coalesced 256B
    lds[lane * 65 + c] = v;                        // conflict-free
#pragma unroll
    for (int j = 0; j < 16; ++j) pacc[j] = fmaf(Wo[j * C_ + c], v, pacc[j]);
#pragma unroll
    for (int j = 0; j < 8; ++j) pacc[16 + j] = fmaf(Ww[j * C_ + c], v, pacc[16 + j]);
  }
  __syncthreads();

  // phase 2: NHWC write, fully coalesced (row px = 64 contiguous floats)
#pragma unroll
  for (int i = 0; i < 16; ++i) {
    const int px = i * 4 + wv;
    ws[(size_t)(p0 + px) * 64 + lane] = lds[px * 65 + lane];
  }
  __syncthreads();

  // phase 3: cross-wave reduction of partials via LDS
#pragma unroll
  for (int j = 0; j < 24; ++j) lds[j * 256 + wv * 64 + lane] = pacc[j];
  __syncthreads();

  float acc[24];
#pragma unroll
  for (int j = 0; j < 24; ++j)
    acc[j] = (lds[j * 256 + lane] + lds[j * 256 + 64 + lane]) +
             (lds[j * 256 + 128 + lane] + lds[j * 256 + 192 + lane]);
#pragma unroll
  for (int j = 0; j < 16; ++j) acc[j] += bo[j];
#pragma unroll
  for (int j = 0; j < 8; ++j) acc[16 + j] += bw[j];

  // phase 4: softmax + mask fold; every wave computes (redundant), wave w writes k=2w,2w+1
  float m = acc[16];
#pragma unroll
  for (int k = 1; k < K_; ++k) m = fmaxf(m, acc[16 + k]);
  float s = 0.f;
#pragma unroll
  for (int k = 0; k < K_; ++k) s += __expf(acc[16 + k] - m);
  const float fm = (mask[p_lane] != 0) ? 1.f : 0.f;
  const float inv = fm / s;

  const int y = hw_lane / W_;
  const int x = hw_lane - y * W_;

  float4* w4p = (float4*)(ws + W4_F);
  int2* xyp = (int2*)(ws + XY_F);
  if (wv == 0) (ws + MK_F)[p_lane] = fm;

#pragma unroll
  for (int kk = 0; kk < 2; ++kk) {
    const int k = wv * 2 + kk;
    const float wtk = __expf(acc[16 + k] - m) * inv;
    const float px = (float)x + acc[2 * k];
    const float py = (float)y + acc[2 * k + 1];
    const float x0f = floorf(px), y0f = floorf(py);
    const float wx = px - x0f, wy = py - y0f;
    const int x0 = (int)x0f, y0 = (int)y0f;
    const int x1 = x0 + 1, y1 = y0 + 1;
    const bool vx0 = ((unsigned)x0 < (unsigned)W_);
    const bool vx1 = ((unsigned)x1 < (unsigned)W_);
    const bool vy0 = ((unsigned)y0 < (unsigned)H_);
    const bool vy1 = ((unsigned)y1 < (unsigned)H_);
    const int cx0 = min(max(x0, 0), W_ - 1), cx1 = min(max(x1, 0), W_ - 1);
    const int cy0 = min(max(y0, 0), H_ - 1), cy1 = min(max(y1, 0), H_ - 1);
    float4 w4;
    w4.x = wtk * (1.f - wx) * (1.f - wy) * ((vx0 && vy0) ? 1.f : 0.f);
    w4.y = wtk * wx * (1.f - wy) * ((vx1 && vy0) ? 1.f : 0.f);
    w4.z = wtk * (1.f - wx) * wy * ((vx0 && vy1) ? 1.f : 0.f);
    w4.w = wtk * wx * wy * ((vx1 && vy1) ? 1.f : 0.f);
    w4p[(size_t)k * NP_ + p_lane] = w4;                       // coalesced 16B
    xyp[(size_t)k * NP_ + p_lane] = make_int2(cx0 | (cx1 << 16), cy0 | (cy1 << 16));
  }
}

// =================== Kernel G2: gather (wave per pixel, lane = corner x cgroup) ===================
__global__ __launch_bounds__(256) void gather2_kernel(
    const float* __restrict__ feat, const float* __restrict__ ws,
    float* __restrict__ out) {
  __shared__ float lds[64 * 65];
  const int bid = blockIdx.x;
  const int sb = (bid & 7) * (NBLK_ / 8) + (bid >> 3);   // bijective XCD swizzle
  const int tid = threadIdx.x;
  const int lane = tid & 63;
  const int wv = tid >> 6;
  const int corner = lane >> 4;     // 0..3
  const int cg = lane & 15;         // channel group of 4
  const int p0 = sb * 64;
  const int b = p0 / HW_;
  const int hw0 = p0 - b * HW_;
  const float4* ft4 = (const float4*)ws;                 // NHWC as float4[NP_*16]
  const float4* w4p = (const float4*)(ws + W4_F);
  const int2* xyp = (const int2*)(ws + XY_F);
  const float* mkp = ws + MK_F;
  const int shx = (corner & 1) * 16;
  const int shy = (corner & 2) * 8;
  const bool cb0 = (corner & 1) != 0;
  const bool cb1 = (corner & 2) != 0;
  const int bHW16 = b * HW_ * 16;   // float4 index base of this batch's feat_t

  for (int i = 0; i < 16; ++i) {
    const int pu = __builtin_amdgcn_readfirstlane(p0 + wv * 16 + i);  // wave-uniform pixel
    float4 r = make_float4(0.f, 0.f, 0.f, 0.f);
    if (mkp[pu] != 0.f) {           // scalar load + scalar branch: true wave skip
#pragma unroll
      for (int k = 0; k < K_; ++k) {
        const float4 w4 = w4p[k * NP_ + pu];   // s_load_dwordx4 broadcast
        const int2 xy = xyp[k * NP_ + pu];     // s_load_dwordx2
        const float wlo = cb0 ? w4.y : w4.x;
        const float whi = cb0 ? w4.w : w4.z;
        const float w = cb1 ? whi : wlo;
        const int xc = (xy.x >> shx) & 0xffff;
        const int yc = (xy.y >> shy) & 0xffff;
        const int idx = yc * W_ + xc;
        const float4 v = ft4[bHW16 + idx * 16 + cg];   // coalesced 1KB wave gather
        r.x = fmaf(w, v.x, r.x);
        r.y = fmaf(w, v.y, r.y);
        r.z = fmaf(w, v.z, r.z);
        r.w = fmaf(w, v.w, r.w);
      }
      // reduce the 4 corner partial sums across lane groups {L, L^16, L^32, L^48}
      r.x += __shfl_xor(r.x, 16); r.y += __shfl_xor(r.y, 16);
      r.z += __shfl_xor(r.z, 16); r.w += __shfl_xor(r.w, 16);
      r.x += __shfl_xor(r.x, 32); r.y += __shfl_xor(r.y, 32);
      r.z += __shfl_xor(r.z, 32); r.w += __shfl_xor(r.w, 32);
    }
    if (corner == 0) {              // lanes 0..15 write the pixel row (zeros if masked)
      const int base = (wv * 16 + i) * 65 + cg * 4;
      lds[base + 0] = r.x; lds[base + 1] = r.y;
      lds[base + 2] = r.z; lds[base + 3] = r.w;
    }
  }
  __syncthreads();

  // epilogue: out = feat + res, coalesced NCHW; wave w handles channels [16w,16w+16)
  const size_t bCHW = (size_t)b * CHW_;
#pragma unroll
  for (int cc = 0; cc < 16; ++cc) {
    const int c = wv * 16 + cc;
    const size_t off = bCHW + (size_t)c * HW_ + hw0 + lane;
    out[off] = feat[off] + lds[lane * 65 + c];
  }
}

// =================== Fallback path (round-2 kernels) ===================
__global__ __launch_bounds__(256) void prep_kernel(
    const float* __restrict__ feat, const int* __restrict__ mask,
    const float* __restrict__ Wo, const float* __restrict__ bo,
    const float* __restrict__ Ww, const float* __restrict__ bw,
    float* __restrict__ ws) {
  const int p = blockIdx.x * 256 + threadIdx.x;
  const int b = p / HW_;
  const int hw = p - b * HW_;
  const int y = hw / W_;
  const int x = hw - y * W_;
  const float* fb = feat + b * CHW_;
  float acc[24];
#pragma unroll
  for (int i = 0; i < 16; ++i) acc[i] = bo[i];
#pragma unroll
  for (int i = 0; i < 8; ++i) acc[16 + i] = bw[i];
#pragma unroll
  for (int c = 0; c < C_; ++c) {
    const float v = fb[c * HW_ + hw];
#pragma unroll
    for (int i = 0; i < 16; ++i) acc[i] = fmaf(Wo[i * C_ + c], v, acc[i]);
#pragma unroll
    for (int i = 0; i < 8; ++i) acc[16 + i] = fmaf(Ww[i * C_ + c], v, acc[16 + i]);
  }
  float m = acc[16];
#pragma unroll
  for (int k = 1; k < K_; ++k) m = fmaxf(m, acc[16 + k]);
  float wt[K_];
  float s = 0.f;
#pragma unroll
  for (int k = 0; k < K_; ++k) { wt[k] = __expf(acc[16 + k] - m); s += wt[k]; }
  const float fm = (mask[p] != 0) ? 1.f : 0.f;
  const float inv = fm / s;
#pragma unroll
  for (int k = 0; k < K_; ++k) {
    ws[k * NP_ + p] = (float)x + acc[2 * k];
    ws[(8 + k) * NP_ + p] = (float)y + acc[2 * k + 1];
    ws[(16 + k) * NP_ + p] = wt[k] * inv;
  }
}

__global__ __launch_bounds__(256) void gather_kernel(
    const float* __restrict__ feat, const float* __restrict__ ws,
    float* __restrict__ out) {
  const int bid = blockIdx.x;
  const int sb = (bid & 7) * (NBLK_ / 8) + (bid >> 3);
  const int lane = threadIdx.x & 63;
  const int wv = threadIdx.x >> 6;
  const int p = sb * 64 + lane;
  const int b = p / HW_;
  const int hw = p - b * HW_;
  const float* fb = feat + b * CHW_;
  const int cbase = wv * 16;
  float wt[K_];
#pragma unroll
  for (int k = 0; k < K_; ++k) wt[k] = ws[(16 + k) * NP_ + p];
  float res[16];
#pragma unroll
  for (int c = 0; c < 16; ++c) res[c] = 0.f;
  float s8 = 0.f;
#pragma unroll
  for (int k = 0; k < K_; ++k) s8 += wt[k];
  if (s8 != 0.f) {
#pragma unroll
    for (int k = 0; k < K_; ++k) {
      const float px = ws[k * NP_ + p];
      const float py = ws[(8 + k) * NP_ + p];
      const float x0f = floorf(px), y0f = floorf(py);
      const float wx = px - x0f, wy = py - y0f;
      const int x0 = (int)x0f, y0 = (int)y0f;
      const int x1 = x0 + 1, y1 = y0 + 1;
      const bool vx0 = ((unsigned)x0 < (unsigned)W_);
      const bool vx1 = ((unsigned)x1 < (unsigned)W_);
      const bool vy0 = ((unsigned)y0 < (unsigned)H_);
      const bool vy1 = ((unsigned)y1 < (unsigned)H_);
      const int cx0 = min(max(x0, 0), W_ - 1), cx1 = min(max(x1, 0), W_ - 1);
      const int cy0 = min(max(y0, 0), H_ - 1), cy1 = min(max(y1, 0), H_ - 1);
      const float wk = wt[k];
      const float w00 = wk * (1.f - wx) * (1.f - wy) * ((vx0 && vy0) ? 1.f : 0.f);
      const float w01 = wk * wx * (1.f - wy) * ((vx1 && vy0) ? 1.f : 0.f);
      const float w10 = wk * (1.f - wx) * wy * ((vx0 && vy1) ? 1.f : 0.f);
      const float w11 = wk * wx * wy * ((vx1 && vy1) ? 1.f : 0.f);
      const int i00 = cy0 * W_ + cx0, i01 = cy0 * W_ + cx1;
      const int i10 = cy1 * W_ + cx0, i11 = cy1 * W_ + cx1;
      const float* fc = fb + cbase * HW_;
#pragma unroll
      for (int c = 0; c < 16; ++c) {
        res[c] = fmaf(w00, fc[i00], res[c]);
        res[c] = fmaf(w01, fc[i01], res[c]);
        res[c] = fmaf(w10, fc[i10], res[c]);
        res[c] = fmaf(w11, fc[i11], res[c]);
        fc += HW_;
      }
    }
  }
#pragma unroll
  for (int c = 0; c < 16; ++c) {
    const int off = b * CHW_ + (cbase + c) * HW_ + hw;
    out[off] = feat[off] + res[c];
  }
}

__global__ __launch_bounds__(256) void fused_kernel(
    const float* __restrict__ feat, const int* __restrict__ mask,
    const float* __restrict__ Wo, const float* __restrict__ bo,
    const float* __restrict__ Ww, const float* __restrict__ bw,
    float* __restrict__ out) {
  const int p = blockIdx.x * blockDim.x + threadIdx.x;
  const int b = p / HW_;
  const int hw = p - b * HW_;
  const int y = hw / W_;
  const int x = hw - y * W_;
  const float* fb = feat + b * CHW_;
  float acc[24];
#pragma unroll
  for (int i = 0; i < 16; ++i) acc[i] = bo[i];
#pragma unroll
  for (int i = 0; i < 8; ++i) acc[16 + i] = bw[i];
#pragma unroll
  for (int c = 0; c < C_; ++c) {
    const float v = fb[c * HW_ + hw];
#pragma unroll
    for (int i = 0; i < 16; ++i) acc[i] = fmaf(Wo[i * C_ + c], v, acc[i]);
#pragma unroll
    for (int i = 0; i < 8; ++i) acc[16 + i] = fmaf(Ww[i * C_ + c], v, acc[16 + i]);
  }
  float m = acc[16];
#pragma unroll
  for (int k = 1; k < K_; ++k) m = fmaxf(m, acc[16 + k]);
  float wt[K_];
  float s = 0.f;
#pragma unroll
  for (int k = 0; k < K_; ++k) { wt[k] = __expf(acc[16 + k] - m); s += wt[k]; }
  const float fm = (mask[p] != 0) ? 1.f : 0.f;
  const float inv = fm / s;
#pragma unroll
  for (int k = 0; k < K_; ++k) wt[k] *= inv;
  float res[C_];
#pragma unroll
  for (int c = 0; c < C_; ++c) res[c] = 0.f;
  if (fm != 0.f) {
#pragma unroll
    for (int k = 0; k < K_; ++k) {
      const float px = (float)x + acc[2 * k];
      const float py = (float)y + acc[2 * k + 1];
      const float x0f = floorf(px), y0f = floorf(py);
      const float wx = px - x0f, wy = py - y0f;
      const int x0 = (int)x0f, y0 = (int)y0f;
      const int x1 = x0 + 1, y1 = y0 + 1;
      const bool vx0 = ((unsigned)x0 < (unsigned)W_);
      const bool vx1 = ((unsigned)x1 < (unsigned)W_);
      const bool vy0 = ((unsigned)y0 < (unsigned)H_);
      const bool vy1 = ((unsigned)y1 < (unsigned)H_);
      const int cx0 = min(max(x0, 0), W_ - 1), cx1 = min(max(x1, 0), W_ - 1);
      const int cy0 = min(max(y0, 0), H_ - 1), cy1 = min(max(y1, 0), H_ - 1);
      const float wk = wt[k];
      const float w00 = wk * (1.f - wx) * (1.f - wy) * ((vx0 && vy0) ? 1.f : 0.f);
      const float w01 = wk * wx * (1.f - wy) * ((vx1 && vy0) ? 1.f : 0.f);
      const float w10 = wk * (1.f - wx) * wy * ((vx0 && vy1) ? 1.f : 0.f);
      const float w11 = wk * wx * wy * ((vx1 && vy1) ? 1.f : 0.f);
      const int i00 = cy0 * W_ + cx0, i01 = cy0 * W_ + cx1;
      const int i10 = cy1 * W_ + cx0, i11 = cy1 * W_ + cx1;
#pragma unroll
      for (int c = 0; c < C_; ++c) {
        const float* fc = fb + c * HW_;
        res[c] += w00 * fc[i00] + w01 * fc[i01] + w10 * fc[i10] + w11 * fc[i11];
      }
    }
  }
#pragma unroll
  for (int c = 0; c < C_; ++c)
    out[b * CHW_ + c * HW_ + hw] = fb[c * HW_ + hw] + res[c];
}

extern "C" void kernel_launch(void* const* d_in, const int* in_sizes, int n_in,
                              void* d_out, int out_size, void* d_ws, size_t ws_size,
                              hipStream_t stream) {
  const float* feat = (const float*)d_in[0];
  const int* mask = (const int*)d_in[1];
  const float* Wo = (const float*)d_in[2];
  const float* bo = (const float*)d_in[3];
  const float* Ww = (const float*)d_in[4];
  const float* bw = (const float*)d_in[5];
  float* out = (float*)d_out;

  if (ws_size >= WS_NEED_NEW) {
    float* ws = (float*)d_ws;
    hipLaunchKernelGGL(prep2_kernel, dim3(NBLK_), dim3(256), 0, stream,
                       feat, mask, Wo, bo, Ww, bw, ws);
    hipLaunchKernelGGL(gather2_kernel, dim3(NBLK_), dim3(256), 0, stream,
                       feat, ws, out);
  } else if (ws_size >= WS_NEED_OLD) {
    float* ws = (float*)d_ws;
    hipLaunchKernelGGL(prep_kernel, dim3(NP_ / 256), dim3(256), 0, stream,
                       feat, mask, Wo, bo, Ww, bw, ws);
    hipLaunchKernelGGL(gather_kernel, dim3(NBLK_), dim3(256), 0, stream,
                       feat, ws, out);
  } else {
    hipLaunchKernelGGL(fused_kernel, dim3(NP_ / 256), dim3(256), 0, stream,
                       feat, mask, Wo, bo, Ww, bw, out);
  }
}

// Round 4
// 86.750 us; speedup vs baseline: 6.2508x; 1.1891x over previous
//
#include <hip/hip_runtime.h>

#define B_ 2
#define C_ 64
#define H_ 192
#define W_ 384
#define K_ 8
constexpr int HW_ = H_ * W_;
constexpr int CHW_ = C_ * HW_;
constexpr int NP_ = B_ * HW_;           // 147456
constexpr int NBLK_ = NP_ / 64;         // 2304, %8==0
constexpr size_t WS_NEED_ = (size_t)NP_ * 64 * sizeof(float);  // 37.7 MB NHWC feat_t

// =================== K1: NCHW -> NHWC transpose ===================
__global__ __launch_bounds__(256) void transpose_kernel(
    const float* __restrict__ feat, float* __restrict__ ft) {
  __shared__ float lds[64 * 65];
  const int tid = threadIdx.x;
  const int lane = tid & 63;
  const int wv = tid >> 6;
  const int p0 = blockIdx.x * 64;
  const int b = p0 / HW_;
  const int hw0 = p0 - b * HW_;
  const float* fb = feat + (size_t)b * CHW_;
#pragma unroll
  for (int cc = 0; cc < 16; ++cc) {
    const int c = wv * 16 + cc;
    lds[lane * 65 + c] = fb[(size_t)c * HW_ + hw0 + lane];   // coalesced 256B
  }
  __syncthreads();
#pragma unroll
  for (int i = 0; i < 16; ++i) {
    const int row = i * 4 + wv;
    ft[(size_t)(p0 + row) * 64 + lane] = lds[row * 65 + lane];  // coalesced 256B
  }
}

// =================== K2: conv + softmax + gather + epilogue ===================
// block = 256 thr = 4 waves, 64 pixels. LDS: rec region (aliased with conv-reduce).
__global__ __launch_bounds__(256) void fusedg_kernel(
    const float* __restrict__ feat, const int* __restrict__ mask,
    const float* __restrict__ Wo, const float* __restrict__ bo,
    const float* __restrict__ Ww, const float* __restrict__ bw,
    const float* __restrict__ ws, float* __restrict__ out) {
  __shared__ float smem[6784];        // 27136 B
  // layout (floats): [0,2048) rec_w4 as float4[8][64]; [2048,2560) rec_ix int[8][64];
  // [2560,2624) mflag[64]; [2624,6784) res[64][65]. conv-reduce [0,6144) aliased.
  float4* rw = (float4*)smem;
  int* ri = (int*)(smem + 2048);
  float* mf = smem + 2560;
  float* resb = smem + 2624;

  const int tid = threadIdx.x;
  const int lane = tid & 63;
  const int wv = tid >> 6;
  const int bid = blockIdx.x;
  const int sb = (bid & 7) * (NBLK_ / 8) + (bid >> 3);   // bijective XCD swizzle
  const int p0 = sb * 64;
  const int b = p0 / HW_;
  const int hw0 = p0 - b * HW_;
  const size_t bCHW = (size_t)b * CHW_;
  const float* fb = feat + bCHW;

  // ---- phase A: conv partials (wave = 16 channels, lane = pixel) ----
  float pacc[24];
#pragma unroll
  for (int j = 0; j < 24; ++j) pacc[j] = 0.f;
#pragma unroll
  for (int cc = 0; cc < 16; ++cc) {
    const int c = wv * 16 + cc;                       // wave-uniform -> s_load weights
    const float v = fb[(size_t)c * HW_ + hw0 + lane]; // coalesced
#pragma unroll
    for (int j = 0; j < 16; ++j) pacc[j] = fmaf(Wo[j * C_ + c], v, pacc[j]);
#pragma unroll
    for (int j = 0; j < 8; ++j) pacc[16 + j] = fmaf(Ww[j * C_ + c], v, pacc[16 + j]);
  }
#pragma unroll
  for (int j = 0; j < 24; ++j) smem[j * 256 + wv * 64 + lane] = pacc[j];
  __syncthreads();

  // ---- phase B: cross-wave reduce (every wave, lane = pixel) ----
  float acc[24];
#pragma unroll
  for (int j = 0; j < 24; ++j)
    acc[j] = (smem[j * 256 + lane] + smem[j * 256 + 64 + lane]) +
             (smem[j * 256 + 128 + lane] + smem[j * 256 + 192 + lane]);
  __syncthreads();   // conv region dead after this; rec/res may overwrite

#pragma unroll
  for (int j = 0; j < 16; ++j) acc[j] += bo[j];
#pragma unroll
  for (int j = 0; j < 8; ++j) acc[16 + j] += bw[j];

  // softmax + mask fold (lane = pixel)
  float m = acc[16];
#pragma unroll
  for (int k = 1; k < K_; ++k) m = fmaxf(m, acc[16 + k]);
  float s = 0.f;
#pragma unroll
  for (int k = 0; k < K_; ++k) s += __expf(acc[16 + k] - m);
  const float fm = (mask[p0 + lane] != 0) ? 1.f : 0.f;
  const float inv = fm / s;
  mf[lane] = fm;                       // every wave writes same value (self-consistent)

  const int hw = hw0 + lane;
  const int y = hw / W_;
  const int x = hw - y * W_;

  // records for this wave's 16 pixels (lanes 16wv..16wv+15 own px = lane)
  if ((lane >> 4) == wv) {
#pragma unroll
    for (int k = 0; k < K_; ++k) {
      const float wtk = __expf(acc[16 + k] - m) * inv;
      const float px = (float)x + acc[2 * k];
      const float py = (float)y + acc[2 * k + 1];
      const float x0f = floorf(px), y0f = floorf(py);
      const float wx = px - x0f, wy = py - y0f;
      const int x0 = (int)x0f, y0 = (int)y0f;
      const int x1 = x0 + 1, y1 = y0 + 1;
      const bool vx0 = ((unsigned)x0 < (unsigned)W_);
      const bool vx1 = ((unsigned)x1 < (unsigned)W_);
      const bool vy0 = ((unsigned)y0 < (unsigned)H_);
      const bool vy1 = ((unsigned)y1 < (unsigned)H_);
      const int cx0 = min(max(x0, 0), W_ - 1), cx1 = min(max(x1, 0), W_ - 1);
      const int cy0 = min(max(y0, 0), H_ - 1), cy1 = min(max(y1, 0), H_ - 1);
      float4 w4;
      w4.x = wtk * (1.f - wx) * (1.f - wy) * ((vx0 && vy0) ? 1.f : 0.f);
      w4.y = wtk * wx * (1.f - wy) * ((vx1 && vy0) ? 1.f : 0.f);
      w4.z = wtk * (1.f - wx) * wy * ((vx0 && vy1) ? 1.f : 0.f);
      w4.w = wtk * wx * wy * ((vx1 && vy1) ? 1.f : 0.f);
      rw[k * 64 + lane] = w4;
      ri[k * 64 + lane] = (cy0 * W_ + cx0) | ((cx1 - cx0) << 18) | ((cy1 - cy0) << 19);
    }
  }

  // ---- phase C: gather (wave = its own 16 pixels; lane = corner x cgroup) ----
  const int corner = lane >> 4;        // 0..3
  const int cg = lane & 15;            // channel group of 4
  const bool cb0 = (corner & 1) != 0;
  const bool cb1 = (corner & 2) != 0;
  const float4* ft4 = (const float4*)ws;
  const int bHW16 = b * HW_ * 16;

  for (int i = 0; i < 16; ++i) {
    const int pxl = wv * 16 + i;       // wave-uniform pixel (own records, no barrier)
    float4 r = make_float4(0.f, 0.f, 0.f, 0.f);
    if (mf[pxl] != 0.f) {              // uniform value -> coherent branch
#pragma unroll
      for (int k = 0; k < K_; ++k) {
        const float4 w4 = rw[k * 64 + pxl];   // ds_read_b128 broadcast
        const int pk = ri[k * 64 + pxl];      // ds_read_b32 broadcast
        const float wlo = cb0 ? w4.y : w4.x;
        const float whi = cb0 ? w4.w : w4.z;
        const float w = cb1 ? whi : wlo;
        int idx = pk & 0x3FFFF;
        idx += cb0 ? ((pk >> 18) & 1) : 0;
        idx += cb1 ? ((pk >> 19) & 1) * W_ : 0;
        const float4 v = ft4[bHW16 + idx * 16 + cg];   // 1KB coalesced wave gather
        r.x = fmaf(w, v.x, r.x);
        r.y = fmaf(w, v.y, r.y);
        r.z = fmaf(w, v.z, r.z);
        r.w = fmaf(w, v.w, r.w);
      }
      r.x += __shfl_xor(r.x, 16); r.y += __shfl_xor(r.y, 16);
      r.z += __shfl_xor(r.z, 16); r.w += __shfl_xor(r.w, 16);
      r.x += __shfl_xor(r.x, 32); r.y += __shfl_xor(r.y, 32);
      r.z += __shfl_xor(r.z, 32); r.w += __shfl_xor(r.w, 32);
    }
    if (corner == 0) {                 // lanes 0..15 write row (zeros if masked)
      const int base = pxl * 65 + cg * 4;
      resb[base + 0] = r.x; resb[base + 1] = r.y;
      resb[base + 2] = r.z; resb[base + 3] = r.w;
    }
  }
  __syncthreads();

  // ---- phase D: epilogue, coalesced NCHW ----
#pragma unroll
  for (int cc = 0; cc < 16; ++cc) {
    const int c = wv * 16 + cc;
    const size_t off = bCHW + (size_t)c * HW_ + hw0 + lane;
    out[off] = feat[off] + resb[lane * 65 + c];
  }
}

// =================== Fallback (ws-free, round-1 fused) ===================
__global__ __launch_bounds__(256) void fused_kernel(
    const float* __restrict__ feat, const int* __restrict__ mask,
    const float* __restrict__ Wo, const float* __restrict__ bo,
    const float* __restrict__ Ww, const float* __restrict__ bw,
    float* __restrict__ out) {
  const int p = blockIdx.x * blockDim.x + threadIdx.x;
  const int b = p / HW_;
  const int hw = p - b * HW_;
  const int y = hw / W_;
  const int x = hw - y * W_;
  const float* fb = feat + b * CHW_;
  float acc[24];
#pragma unroll
  for (int i = 0; i < 16; ++i) acc[i] = bo[i];
#pragma unroll
  for (int i = 0; i < 8; ++i) acc[16 + i] = bw[i];
#pragma unroll
  for (int c = 0; c < C_; ++c) {
    const float v = fb[c * HW_ + hw];
#pragma unroll
    for (int i = 0; i < 16; ++i) acc[i] = fmaf(Wo[i * C_ + c], v, acc[i]);
#pragma unroll
    for (int i = 0; i < 8; ++i) acc[16 + i] = fmaf(Ww[i * C_ + c], v, acc[16 + i]);
  }
  float m = acc[16];
#pragma unroll
  for (int k = 1; k < K_; ++k) m = fmaxf(m, acc[16 + k]);
  float wt[K_];
  float s = 0.f;
#pragma unroll
  for (int k = 0; k < K_; ++k) { wt[k] = __expf(acc[16 + k] - m); s += wt[k]; }
  const float fm = (mask[p] != 0) ? 1.f : 0.f;
  const float inv = fm / s;
#pragma unroll
  for (int k = 0; k < K_; ++k) wt[k] *= inv;
  float res[C_];
#pragma unroll
  for (int c = 0; c < C_; ++c) res[c] = 0.f;
  if (fm != 0.f) {
#pragma unroll
    for (int k = 0; k < K_; ++k) {
      const float px = (float)x + acc[2 * k];
      const float py = (float)y + acc[2 * k + 1];
      const float x0f = floorf(px), y0f = floorf(py);
      const float wx = px - x0f, wy = py - y0f;
      const int x0 = (int)x0f, y0 = (int)y0f;
      const int x1 = x0 + 1, y1 = y0 + 1;
      const bool vx0 = ((unsigned)x0 < (unsigned)W_);
      const bool vx1 = ((unsigned)x1 < (unsigned)W_);
      const bool vy0 = ((unsigned)y0 < (unsigned)H_);
      const bool vy1 = ((unsigned)y1 < (unsigned)H_);
      const int cx0 = min(max(x0, 0), W_ - 1), cx1 = min(max(x1, 0), W_ - 1);
      const int cy0 = min(max(y0, 0), H_ - 1), cy1 = min(max(y1, 0), H_ - 1);
      const float wk = wt[k];
      const float w00 = wk * (1.f - wx) * (1.f - wy) * ((vx0 && vy0) ? 1.f : 0.f);
      const float w01 = wk * wx * (1.f - wy) * ((vx1 && vy0) ? 1.f : 0.f);
      const float w10 = wk * (1.f - wx) * wy * ((vx0 && vy1) ? 1.f : 0.f);
      const float w11 = wk * wx * wy * ((vx1 && vy1) ? 1.f : 0.f);
      const int i00 = cy0 * W_ + cx0, i01 = cy0 * W_ + cx1;
      const int i10 = cy1 * W_ + cx0, i11 = cy1 * W_ + cx1;
#pragma unroll
      for (int c = 0; c < C_; ++c) {
        const float* fc = fb + c * HW_;
        res[c] += w00 * fc[i00] + w01 * fc[i01] + w10 * fc[i10] + w11 * fc[i11];
      }
    }
  }
#pragma unroll
  for (int c = 0; c < C_; ++c)
    out[b * CHW_ + c * HW_ + hw] = fb[c * HW_ + hw] + res[c];
}

extern "C" void kernel_launch(void* const* d_in, const int* in_sizes, int n_in,
                              void* d_out, int out_size, void* d_ws, size_t ws_size,
                              hipStream_t stream) {
  const float* feat = (const float*)d_in[0];
  const int* mask = (const int*)d_in[1];
  const float* Wo = (const float*)d_in[2];
  const float* bo = (const float*)d_in[3];
  const float* Ww = (const float*)d_in[4];
  const float* bw = (const float*)d_in[5];
  float* out = (float*)d_out;

  if (ws_size >= WS_NEED_) {
    float* ws = (float*)d_ws;
    hipLaunchKernelGGL(transpose_kernel, dim3(NBLK_), dim3(256), 0, stream,
                       feat, ws);
    hipLaunchKernelGGL(fusedg_kernel, dim3(NBLK_), dim3(256), 0, stream,
                       feat, mask, Wo, bo, Ww, bw, ws, out);
  } else {
    hipLaunchKernelGGL(fused_kernel, dim3(NP_ / 256), dim3(256), 0, stream,
                       feat, mask, Wo, bo, Ww, bw, out);
  }
}